// Round 7
// baseline (1195.877 us; speedup 1.0000x reference)
//
#include <hip/hip_runtime.h>
#include <stdint.h>

typedef short s16x4 __attribute__((ext_vector_type(4)));
typedef short s16x8 __attribute__((ext_vector_type(8)));
typedef float f32x4 __attribute__((ext_vector_type(4)));

__device__ __forceinline__ short f2bf(float f) {
  unsigned u = __builtin_bit_cast(unsigned, f);
  u += 0x7fffu + ((u >> 16) & 1u);   // RNE
  return (short)(u >> 16);
}

__device__ __forceinline__ void gll16(const short* g, short* l) {
  __builtin_amdgcn_global_load_lds(
      (const __attribute__((address_space(1))) unsigned*)g,
      (__attribute__((address_space(3))) unsigned*)l, 16, 0, 0);
}

#define MFMA(a, b, c) __builtin_amdgcn_mfma_f32_16x16x32_bf16(a, b, c, 0, 0, 0)

// ---------------- pack x: NCHW f32 -> padded NHWC bf16 (16,66,66,512); border zeroed here ----------------
__global__ __launch_bounds__(256) void pack_x(const float* __restrict__ x, short* __restrict__ xp) {
  int b = blockIdx.x; int n = b / 66; int hp = b % 66;
  int t = threadIdx.x;
  short* rowd = xp + ((size_t)n * 66 + hp) * 66 * 512;
  const s16x8 z = (s16x8){0, 0, 0, 0, 0, 0, 0, 0};
  if (hp == 0 || hp == 65) {           // full padded row = 66*512 shorts = 4224 s16x8
    for (int i = t; i < 4224; i += 256) *(s16x8*)(rowd + i * 8) = z;
    return;
  }
  if (t < 128) {                        // zero w=0 and w=65 columns (512 shorts each)
    int wcol = (t >> 6) ? 65 : 0;
    *(s16x8*)(rowd + wcol * 512 + (t & 63) * 8) = z;
  }
  int h = hp - 1;
  int l = t & 63, wv = t >> 6;
  const float* xs = x + (size_t)n * (512 * 4096) + h * 64 + l;
  short* xd = rowd + (l + 1) * 512;
  for (int c0 = wv * 8; c0 < 512; c0 += 32) {
    s16x8 v;
#pragma unroll
    for (int j = 0; j < 8; ++j) v[j] = f2bf(xs[(size_t)(c0 + j) * 4096]);
    *(s16x8*)(xd + c0) = v;
  }
}

// ---------------- pack conv weights: [co][ci][3][3] f32 -> [co][kyx*512+ci] bf16 ----------------
__global__ __launch_bounds__(256) void pack_w(const float* __restrict__ qw, const float* __restrict__ kvw,
                                              short* __restrict__ wqkv) {
  int co = blockIdx.x;  // 0..1535
  const float* src = (co < 512) ? (qw + (size_t)co * 4608) : (kvw + (size_t)(co - 512) * 4608);
  short* dst = wqkv + (size_t)co * 4608;
  for (int ci = threadIdx.x; ci < 512; ci += 256) {   // writes 128B-coalesced per kyx
    float v[9];
#pragma unroll
    for (int j = 0; j < 9; ++j) v[j] = src[ci * 9 + j];
#pragma unroll
    for (int j = 0; j < 9; ++j) dst[j * 512 + ci] = f2bf(v[j]);
  }
}

__global__ __launch_bounds__(256) void pack_pw(const float* __restrict__ pw, short* __restrict__ wp) {
  int i = blockIdx.x * 256 + threadIdx.x;  // grid 1024 * 256 = 262144
  wp[i] = f2bf(pw[i]);
}

// ---------------- fused qkv conv3x3 as implicit GEMM, 256x256 tile, BK=64, 8-phase pipeline ----------------
// M = 65536 spatial, N = 1536 out-channels, K = 4608, 72 K-tiles of 64; 2 K-tiles per iter.
// 8 waves (2M x 4N), per-wave C = 128x64. LDS: 2 dbuf x (A 32KB + B 32KB) = 128KB.
// Per-phase: {ds_read subtile; stage 1 half-tile (2 gll16); [vmcnt]; barrier; lgkm0; 16 MFMA; barrier}.
// Stage ledger (lag-1 behind frees): per iter i (tiles T=2i buf0, T+1 buf1, staging T+2/T+3):
//   ph2:B0@buf0 ph3:B1@buf0 ph4:A0@buf0 ph5:A1@buf0 ph6:B0@buf1 ph7:B1@buf1 ph0':A0@buf1 ph1':A1@buf1
// (B-halves of a buf are last ds_read in ph1/ph5; A-halves in ph2/ph6 -> all stages write freed slots.)
// vmcnt(4) at ph3/ph7 (2 half-tiles = 4 loads in flight); final iter peels to vmcnt(0) at ph3.
__global__ __launch_bounds__(512, 2) void conv_gemm(const short* __restrict__ xp, const short* __restrict__ wqkv,
                                                    const float* __restrict__ qb, const float* __restrict__ kvb,
                                                    short* __restrict__ qkv) {
  extern __shared__ short lds[];
  const int NI = 36, QTOT = 280;                 // NT=72 tiles; QTOT = 4*(NT-2) stage-halves
  int bid = blockIdx.x;
  int swz = (bid & 7) * 192 + (bid >> 3);        // bijective XCD swizzle (1536 % 8 == 0)
  int mt = swz / 6, ntile = swz - mt * 6;        // nt fastest: each XCD owns 32 contiguous M-panels
  int s0 = mt << 8, co0 = ntile << 8;
  int t = threadIdx.x, l = t & 63, wv = t >> 6;
  int r = l & 15, kq = l >> 4;
  int wm = wv >> 2, wn = wv & 3;

  // staging source offsets (elements); k16 chunk pre-XOR'd so LDS content is swizzled
  int trow = t >> 3;
  int k16 = (t & 7) ^ (trow & 7);
  int asrcO[4], bsrcO[4];
#pragma unroll
  for (int i = 0; i < 4; ++i) {       // slot i = rows i*64..i*64+63 of the 256-row tile
    int row = i * 64 + trow;
    int s = s0 + row;
    int nn = s >> 12, hh = (s >> 6) & 63, ww = s & 63;
    asrcO[i] = ((nn * 66 + hh) * 66 + ww) * 512 + k16 * 8;
    bsrcO[i] = (co0 + row) * 4608 + k16 * 8;
  }
  int ldsA = wv << 10;                // bytes; + buf*32768 + slot*8192 (wave-uniform base)
  int ldsB = 65536 + (wv << 10);

  // fragment read bases (bytes)
  int aRB = (wm << 14) + (r << 7);
  int bRB = 65536 + ((wn >> 1) << 14) + ((((wn & 1) << 6) + r) << 7);
  int cb0 = (kq ^ (r & 7)) << 4, cb1 = ((4 + kq) ^ (r & 7)) << 4;

  f32x4 acc[8][4];
#pragma unroll
  for (int i = 0; i < 8; ++i)
#pragma unroll
    for (int j = 0; j < 4; ++j) acc[i][j] = (f32x4){0.f, 0.f, 0.f, 0.f};

  auto stageA = [&](int tile, int ha) {
    int kyx = tile >> 3; int ky = (kyx * 11) >> 5; int kx = kyx - ky * 3;  // kyx/3 for 0..8
    int aoff = (ky * 66 + kx) * 512 + (tile & 7) * 64;
    int base = ldsA + ((tile & 1) << 15) + (ha << 14);
#pragma unroll
    for (int j = 0; j < 2; ++j)
      gll16(xp + asrcO[2 * ha + j] + aoff, lds + ((base + (j << 13)) >> 1));
  };
  auto stageB = [&](int tile, int hb) {
    int boff = tile * 64;
    int base = ldsB + ((tile & 1) << 15) + (hb << 14);
#pragma unroll
    for (int j = 0; j < 2; ++j)
      gll16(wqkv + bsrcO[2 * hb + j] + boff, lds + ((base + (j << 13)) >> 1));
  };
  auto stageQ = [&](int q) {          // q&3: 0:B-h0 1:B-h1 2:A-h0 3:A-h1; tile = 2+q/4
    int tile = 2 + (q >> 2);
    int typ = q & 3;
    if (typ & 2) stageA(tile, typ & 1); else stageB(tile, typ & 1);
  };

#define RD16(X) (*(const s16x8*)(lds + ((X) >> 1)))
#define RD_AF(D, SUB) do { _Pragma("unroll") for (int m_ = 0; m_ < 4; ++m_) { \
    af[m_][0] = RD16((D) + aRB + ((SUB) << 13) + (m_ << 11) + cb0); \
    af[m_][1] = RD16((D) + aRB + ((SUB) << 13) + (m_ << 11) + cb1); } } while (0)
#define RD_B(BF, D, SUB) do { _Pragma("unroll") for (int n_ = 0; n_ < 2; ++n_) { \
    BF[n_][0] = RD16((D) + bRB + ((SUB) << 12) + (n_ << 11) + cb0); \
    BF[n_][1] = RD16((D) + bRB + ((SUB) << 12) + (n_ << 11) + cb1); } } while (0)
#define MM(MB, NB, BF) do { __builtin_amdgcn_s_setprio(1); \
    _Pragma("unroll") for (int m_ = 0; m_ < 4; ++m_) \
    _Pragma("unroll") for (int n_ = 0; n_ < 2; ++n_) { \
      acc[(MB) + m_][(NB) + n_] = MFMA(af[m_][0], BF[n_][0], acc[(MB) + m_][(NB) + n_]); \
      acc[(MB) + m_][(NB) + n_] = MFMA(af[m_][1], BF[n_][1], acc[(MB) + m_][(NB) + n_]); } \
    __builtin_amdgcn_s_setprio(0); } while (0)
#define BARR() do { __builtin_amdgcn_s_barrier(); __builtin_amdgcn_sched_barrier(0); } while (0)
#define LGKM0() do { asm volatile("s_waitcnt lgkmcnt(0)" ::: "memory"); \
    __builtin_amdgcn_sched_barrier(0); } while (0)

  s16x8 af[4][2], b0[2][2], b1[2][2];

  // prologue: stage tiles 0 (buf0) and 1 (buf1)
  stageB(0, 0); stageB(0, 1); stageA(0, 0); stageA(0, 1);
  stageB(1, 0); stageB(1, 1); stageA(1, 0); stageA(1, 1);
  asm volatile("s_waitcnt vmcnt(8)" ::: "memory");   // tile 0 landed; tile 1 in flight
  BARR();

  for (int i = 0; i < NI; ++i) {
    int q0 = 8 * i;
    // ph0: quad(m0,n0) tile T (buf0)
    RD_AF(0, 0); RD_B(b0, 0, 0);
    if (i > 0) stageQ(q0 - 2);
    BARR(); LGKM0(); MM(0, 0, b0); BARR();
    // ph1: quad(m0,n1)
    RD_B(b1, 0, 1);
    if (i > 0) stageQ(q0 - 1);
    BARR(); LGKM0(); MM(0, 2, b1); BARR();
    // ph2: quad(m1,n1)
    RD_AF(0, 1);
    if (q0 < QTOT) stageQ(q0);
    BARR(); LGKM0(); MM(4, 2, b1); BARR();
    // ph3: quad(m1,n0); counted vmcnt confirms buf1 (tile T+1) staged
    if (q0 + 1 < QTOT) stageQ(q0 + 1);
    if (i == NI - 1) { asm volatile("s_waitcnt vmcnt(0)" ::: "memory"); }
    else             { asm volatile("s_waitcnt vmcnt(4)" ::: "memory"); }
    BARR(); MM(4, 0, b0); BARR();
    // ph4: quad(m0,n0) tile T+1 (buf1)
    RD_AF(32768, 0); RD_B(b0, 32768, 0);
    if (q0 + 2 < QTOT) stageQ(q0 + 2);
    BARR(); LGKM0(); MM(0, 0, b0); BARR();
    // ph5: quad(m0,n1)
    RD_B(b1, 32768, 1);
    if (q0 + 3 < QTOT) stageQ(q0 + 3);
    BARR(); LGKM0(); MM(0, 2, b1); BARR();
    // ph6: quad(m1,n1)
    RD_AF(32768, 1);
    if (q0 + 4 < QTOT) stageQ(q0 + 4);
    BARR(); LGKM0(); MM(4, 2, b1); BARR();
    // ph7: quad(m1,n0); counted vmcnt confirms buf0 (tile T+2) staged
    if (q0 + 5 < QTOT) stageQ(q0 + 5);
    if (i < NI - 1) asm volatile("s_waitcnt vmcnt(4)" ::: "memory");
    BARR(); MM(4, 0, b0); BARR();
  }

  // epilogue: bias + bf16 store to NCHW qkv
#pragma unroll
  for (int m8 = 0; m8 < 8; ++m8) {
    int srow = s0 + wm * 128 + m8 * 16 + kq * 4;
    int nn = srow >> 12, sl = srow & 4095;
#pragma unroll
    for (int n4 = 0; n4 < 4; ++n4) {
      int col = co0 + wn * 64 + n4 * 16 + r;
      float bias = (col < 512) ? qb[col] : kvb[col - 512];
      s16x4 v;
#pragma unroll
      for (int j = 0; j < 4; ++j) v[j] = f2bf(acc[m8][n4][j] + bias);
      *(s16x4*)(qkv + ((size_t)nn * 1536 + col) * 4096 + sl) = v;
    }
  }
#undef RD16
#undef RD_AF
#undef RD_B
#undef MM
#undef BARR
#undef LGKM0
}

// ---------------- per-(n,ch) attention: O = softmax(Q K^T) V on 64x64 planes ----------------
__global__ __launch_bounds__(64) void attn(const short* __restrict__ qkv, short* __restrict__ o) {
  __shared__ short VT[64 * 72];  // V^T, pitch 72
  __shared__ short P[64 * 72];   // softmax(S) as [i][k]
  int slice = blockIdx.x;
  int n = slice >> 9, ch = slice & 511;
  const short* Q = qkv + ((size_t)n * 1536 + ch) * 4096;
  const short* K = qkv + ((size_t)n * 1536 + 512 + ch) * 4096;
  const short* V = qkv + ((size_t)n * 1536 + 1024 + ch) * 4096;
  int l = threadIdx.x;
  int r16 = l & 15, hi = l >> 4;

  s16x8 vr[8];
#pragma unroll
  for (int j = 0; j < 8; ++j) vr[j] = *(const s16x8*)(V + l * 64 + j * 8);
#pragma unroll
  for (int a = 0; a < 8; ++a)
#pragma unroll
    for (int e = 0; e < 8; ++e) VT[(a * 8 + e) * 72 + l] = vr[a][e];

  f32x4 st[4][4];
#pragma unroll
  for (int i = 0; i < 4; ++i)
#pragma unroll
    for (int j = 0; j < 4; ++j) st[i][j] = (f32x4){0.f, 0.f, 0.f, 0.f};
#pragma unroll
  for (int kc = 0; kc < 2; ++kc) {
    s16x8 kf[4], qf[4];
#pragma unroll
    for (int mt = 0; mt < 4; ++mt) kf[mt] = *(const s16x8*)(K + (mt * 16 + r16) * 64 + kc * 32 + hi * 8);
#pragma unroll
    for (int nt = 0; nt < 4; ++nt) qf[nt] = *(const s16x8*)(Q + (nt * 16 + r16) * 64 + kc * 32 + hi * 8);
#pragma unroll
    for (int mt = 0; mt < 4; ++mt)
#pragma unroll
      for (int nt = 0; nt < 4; ++nt) st[mt][nt] = MFMA(kf[mt], qf[nt], st[mt][nt]);
  }
  __syncthreads();

#pragma unroll
  for (int nt = 0; nt < 4; ++nt) {
    float mx = -1e30f;
#pragma unroll
    for (int mt = 0; mt < 4; ++mt)
#pragma unroll
      for (int j = 0; j < 4; ++j) mx = fmaxf(mx, st[mt][nt][j]);
    mx = fmaxf(mx, __shfl_xor(mx, 16, 64));
    mx = fmaxf(mx, __shfl_xor(mx, 32, 64));
    float sum = 0.f;
#pragma unroll
    for (int mt = 0; mt < 4; ++mt)
#pragma unroll
      for (int j = 0; j < 4; ++j) {
        float p = __expf(st[mt][nt][j] - mx);
        st[mt][nt][j] = p;
        sum += p;
      }
    sum += __shfl_xor(sum, 16, 64);
    sum += __shfl_xor(sum, 32, 64);
    float inv = 1.0f / sum;
#pragma unroll
    for (int mt = 0; mt < 4; ++mt) {
      s16x4 pv;
#pragma unroll
      for (int j = 0; j < 4; ++j) pv[j] = f2bf(st[mt][nt][j] * inv);
      *(s16x4*)(P + (nt * 16 + r16) * 72 + mt * 16 + hi * 4) = pv;
    }
  }
  __syncthreads();

  f32x4 ot[4][4];
#pragma unroll
  for (int i = 0; i < 4; ++i)
#pragma unroll
    for (int j = 0; j < 4; ++j) ot[i][j] = (f32x4){0.f, 0.f, 0.f, 0.f};
#pragma unroll
  for (int kc = 0; kc < 2; ++kc) {
    s16x8 vf[4], pf[4];
#pragma unroll
    for (int wt = 0; wt < 4; ++wt) vf[wt] = *(const s16x8*)(VT + (wt * 16 + r16) * 72 + kc * 32 + hi * 8);
#pragma unroll
    for (int nt = 0; nt < 4; ++nt) pf[nt] = *(const s16x8*)(P + (nt * 16 + r16) * 72 + kc * 32 + hi * 8);
#pragma unroll
    for (int wt = 0; wt < 4; ++wt)
#pragma unroll
      for (int nt = 0; nt < 4; ++nt) ot[wt][nt] = MFMA(vf[wt], pf[nt], ot[wt][nt]);
  }

  int cho = (ch & 31) * 16 + (ch >> 5);
  short* os = o + ((size_t)n * 512 + cho) * 4096;
#pragma unroll
  for (int wt = 0; wt < 4; ++wt)
#pragma unroll
    for (int nt = 0; nt < 4; ++nt) {
      int i = nt * 16 + r16;
      int w = wt * 16 + (hi << 2);
      s16x4 v;
#pragma unroll
      for (int j = 0; j < 4; ++j) v[j] = f2bf(ot[wt][nt][j]);
      *(s16x4*)(os + i * 64 + w) = v;
    }
}

// ---------------- transpose attention output: NCHW bf16 -> NHWC bf16 ----------------
__global__ __launch_bounds__(256) void transpose_o(const short* __restrict__ o, short* __restrict__ onhwc) {
  int b = blockIdx.x; int n = b >> 6; int h = b & 63;
  int t = threadIdx.x; int l = t & 63; int wv = t >> 6;
  const short* os = o + (size_t)n * (512 * 4096) + h * 64 + l;
  short* od = onhwc + (((size_t)n * 64 + h) * 64 + l) * 512;
  for (int c0 = wv * 8; c0 < 512; c0 += 32) {
    s16x8 v;
#pragma unroll
    for (int j = 0; j < 8; ++j) v[j] = os[(size_t)(c0 + j) * 4096];
    *(s16x8*)(od + c0) = v;
  }
}

// ---------------- proj 1x1 conv: GEMM M=65536, N=512, K=512 -> f32 NCHW out ----------------
__global__ __launch_bounds__(256, 2) void proj_gemm(const short* __restrict__ A, const short* __restrict__ W,
                                                    const float* __restrict__ pb, float* __restrict__ out) {
  __shared__ short Alds[128 * 32];
  __shared__ short Blds[128 * 32];
  int bid = blockIdx.x;
  int ntile = bid & 3, mtile = bid >> 2;
  int s0 = mtile * 128, co0 = ntile * 128;
  int t = threadIdx.x, l = t & 63, wv = t >> 6;
  int rl = l >> 2, kq = l & 3;
  size_t bA0 = (size_t)(s0 + wv * 16 + rl) * 512 + kq * 8;
  size_t bA1 = bA0 + (size_t)64 * 512;
  size_t bB0 = (size_t)(co0 + wv * 16 + rl) * 512 + kq * 8;
  size_t bB1 = bB0 + (size_t)64 * 512;
  short* lA0 = Alds + wv * 16 * 32;
  short* lA1 = Alds + (64 + wv * 16) * 32;
  short* lB0 = Blds + wv * 16 * 32;
  short* lB1 = Blds + (64 + wv * 16) * 32;
  int wm = wv >> 1, wn = wv & 1;
  int la = (wm * 64 + (l & 15)) * 32 + (l >> 4) * 8;
  int lb = (wn * 64 + (l & 15)) * 32 + (l >> 4) * 8;

  f32x4 acc[4][4];
#pragma unroll
  for (int i = 0; i < 4; ++i)
#pragma unroll
    for (int j = 0; j < 4; ++j) acc[i][j] = (f32x4){0.f, 0.f, 0.f, 0.f};

  for (int cs = 0; cs < 16; ++cs) {
    int o = cs * 32;
    gll16(A + bA0 + o, lA0);
    gll16(A + bA1 + o, lA1);
    gll16(W + bB0 + o, lB0);
    gll16(W + bB1 + o, lB1);
    __syncthreads();
    s16x8 af[4], bf[4];
#pragma unroll
    for (int mt = 0; mt < 4; ++mt) af[mt] = *(const s16x8*)(Alds + la + mt * 16 * 32);
#pragma unroll
    for (int nt = 0; nt < 4; ++nt) bf[nt] = *(const s16x8*)(Blds + lb + nt * 16 * 32);
#pragma unroll
    for (int mt = 0; mt < 4; ++mt)
#pragma unroll
      for (int nt = 0; nt < 4; ++nt) acc[mt][nt] = MFMA(af[mt], bf[nt], acc[mt][nt]);
    __syncthreads();
  }
#pragma unroll
  for (int mt = 0; mt < 4; ++mt) {
    int srow = s0 + wm * 64 + mt * 16 + ((l >> 4) << 2);
    int n = srow >> 12, sl = srow & 4095;
#pragma unroll
    for (int nt = 0; nt < 4; ++nt) {
      int col = co0 + wn * 64 + nt * 16 + (l & 15);
      float bias = pb[col];
      f32x4 v;
#pragma unroll
      for (int j = 0; j < 4; ++j) v[j] = acc[mt][nt][j] + bias;
      *(f32x4*)(out + ((size_t)n * 512 + col) * 4096 + sl) = v;
    }
  }
}

extern "C" void kernel_launch(void* const* d_in, const int* in_sizes, int n_in,
                              void* d_out, int out_size, void* d_ws, size_t ws_size,
                              hipStream_t stream) {
  const float* x   = (const float*)d_in[0];
  const float* qw  = (const float*)d_in[1];
  const float* qb  = (const float*)d_in[2];
  const float* kvw = (const float*)d_in[3];
  const float* kvb = (const float*)d_in[4];
  const float* pw  = (const float*)d_in[5];
  const float* pb  = (const float*)d_in[6];

  char* ws = (char*)d_ws;
  short* xp    = (short*)(ws);               // 71,368,704 B : padded NHWC bf16 x
  short* wqkv  = (short*)(ws + 71368704);    // 14,155,776 B : packed qkv conv weights
  short* qkv   = (short*)(ws + 85524480);    // 201,326,592 B: conv out, NCHW bf16 (q|k|v)
  short* wproj = (short*)(ws + 286851072);   //    524,288 B : packed proj weights
  short* o_nchw = (short*)d_out;             // reuse d_out front as bf16 attn-out scratch
  short* o_nhwc = xp;                        // reuse xp region (conv done by then)
  float* out = (float*)d_out;

  // Host-side attribute set; unconditional (no static guards), graph-capture-safe.
  hipFuncSetAttribute(reinterpret_cast<const void*>(conv_gemm),
                      hipFuncAttributeMaxDynamicSharedMemorySize, 131072);

  pack_x<<<1056, 256, 0, stream>>>(x, xp);   // includes border zeroing (no memset)
  pack_w<<<1536, 256, 0, stream>>>(qw, kvw, wqkv);
  pack_pw<<<1024, 256, 0, stream>>>(pw, wproj);
  conv_gemm<<<1536, 512, 131072, stream>>>(xp, wqkv, qb, kvb, qkv);
  attn<<<8192, 64, 0, stream>>>(qkv, o_nchw);
  transpose_o<<<1024, 256, 0, stream>>>(o_nchw, o_nhwc);
  proj_gemm<<<2048, 256, 0, stream>>>(o_nhwc, wproj, pb, out);
}